// Round 3
// baseline (228.040 us; speedup 1.0000x reference)
//
#include <hip/hip_runtime.h>

#define IMW 1024
#define IMH 1024
#define NB  8
#define HALF 25
#define STRIP 32
#define NCELL 64
#define RPB 4            // rows per block = waves per block

#define W_R ((double)0.2989f)
#define W_G ((double)0.5870f)
#define W_B ((double)0.1140f)
#define INV_AREA (1.0 / 2601.0)

__device__ __forceinline__ int refl(int i, int n) {
    if (i < 0) i = -i;
    if (i >= n) i = 2 * n - 2 - i;
    return i;
}

// LDS swizzle: pad 1 slot per 32 entries so stride-16 f32 access maps each
// lane pair to a distinct bank (banks = 33k+c mod 32 -> exact 2-way = free).
__device__ __forceinline__ int swz(int p) { return p + (p >> 5); }

// init 64 min-cells (all-ones) and 64 max-cells (zero); g>=0 so f32 bit-order == uint order
__global__ void k0_init(unsigned* cells) {
    cells[threadIdx.x] = (threadIdx.x < NCELL) ? 0xFFFFFFFFu : 0u;
}

// Wave-per-row sliding-window row pass. Lane l owns 16 contiguous pixels.
// gray (f32) staged in a per-row LDS buffer; window sums built once with 51
// reads then slid with v += g[p+26]-g[p-25], all accumulation in f64 over
// exact f32 grays -> same numerics class as the verified cumsum version.
// No scan, no f64 shuffles, no cross-wave coupling: 8192 independent waves.
__global__ __launch_bounds__(256) void k1_rowpass(const float* __restrict__ in,
                                                  float2* __restrict__ hp,
                                                  float* __restrict__ gray,
                                                  unsigned* __restrict__ cells) {
    __shared__ float gb[RPB][1056];         // 16.9 KB: swizzled 1024-entry row buffers
    const int t = threadIdx.x;
    const int lane = t & 63, w = t >> 6;
    const int row = blockIdx.x * RPB + w;   // 0 .. NB*IMH-1
    const long long base = (long long)row * IMW;
    const int p0 = lane * 16;

    // ---- load 16 px RGB, compute gray (f64, round to f32), stage to LDS ----
    const float4* p4 = (const float4*)(in + base * 3);
    float lmin = 1e30f, lmax = -1e30f;
    #pragma unroll
    for (int q = 0; q < 4; q++) {
        float4 f0 = p4[12*lane + 3*q + 0];
        float4 f1 = p4[12*lane + 3*q + 1];
        float4 f2 = p4[12*lane + 3*q + 2];
        float g0 = (float)((double)f0.x*W_R + (double)f0.y*W_G + (double)f0.z*W_B);
        float g1 = (float)((double)f0.w*W_R + (double)f1.x*W_G + (double)f1.y*W_B);
        float g2 = (float)((double)f1.z*W_R + (double)f1.w*W_G + (double)f2.x*W_B);
        float g3 = (float)((double)f2.y*W_R + (double)f2.z*W_G + (double)f2.w*W_B);
        int p = p0 + 4*q;
        gb[w][swz(p+0)] = g0; gb[w][swz(p+1)] = g1;
        gb[w][swz(p+2)] = g2; gb[w][swz(p+3)] = g3;
        ((float4*)(gray + base + p0))[q] = make_float4(g0, g1, g2, g3);
        lmin = fminf(lmin, fminf(fminf(g0, g1), fminf(g2, g3)));
        lmax = fmaxf(lmax, fmaxf(fmaxf(g0, g1), fmaxf(g2, g3)));
    }

    // per-wave min/max -> hierarchical atomic cells
    for (int off = 32; off; off >>= 1) {
        lmin = fminf(lmin, __shfl_down(lmin, off));
        lmax = fmaxf(lmax, __shfl_down(lmax, off));
    }
    if (lane == 0) {
        int cell = row & (NCELL - 1);
        atomicMin(&cells[cell], __float_as_uint(lmin));
        atomicMax(&cells[NCELL + cell], __float_as_uint(lmax));
    }

    __syncthreads();   // insurance only: each wave reads only its own row buffer

    // ---- prologue: 51-tap window at p0, 3 independent f64 accumulators ----
    double s1a = 0.0, s1b = 0.0, s1c = 0.0;
    double s2a = 0.0, s2b = 0.0, s2c = 0.0;
    #pragma unroll
    for (int i = 0; i < 51; i += 3) {
        double d0 = (double)gb[w][swz(refl(p0 - HALF + i + 0, IMW))];
        double d1 = (double)gb[w][swz(refl(p0 - HALF + i + 1, IMW))];
        double d2 = (double)gb[w][swz(refl(p0 - HALF + i + 2, IMW))];
        s1a += d0; s2a = fma(d0, d0, s2a);
        s1b += d1; s2b = fma(d1, d1, s2b);
        s1c += d2; s2c = fma(d2, d2, s2c);
    }
    double v1 = (s1a + s1b) + s1c;
    double v2 = (s2a + s2b) + s2c;

    // ---- slide across the 16 owned pixels, paired float4 hp stores ----
    float4* hp4 = (float4*)(hp + base + p0);
    float hx0 = 0.f, hy0 = 0.f;
    #pragma unroll
    for (int j = 0; j < 16; j++) {
        float hx = (float)v1, hy = (float)v2;
        if (j & 1) hp4[j >> 1] = make_float4(hx0, hy0, hx, hy);
        else { hx0 = hx; hy0 = hy; }
        if (j != 15) {
            int p = p0 + j;
            double ga = (double)gb[w][swz(refl(p + HALF + 1, IMW))];
            double gs = (double)gb[w][swz(refl(p - HALF,     IMW))];
            v1 += ga - gs;
            v2 += ga * ga - gs * gs;
        }
    }
}

// Column pass: 1 column/thread, vertical running 51-window over interleaved hp.
// STRIP=32 (round-1 config: 1024 blocks, measured best; STRIP=16's init
// amplification cost more than the extra occupancy bought).
// XCD-swizzled linear grid: batch = id&7 -> one image per XCD; consecutive ids
// walk y-strips so overlapping 51-row windows share L2.
// Sqrt/div-free Sauvola compare: g > m(1+0.2(s/r-1)) <=> A>0 && A^2 r^2 > 0.04 m^2 var.
__global__ __launch_bounds__(256) void k2_colpass(const float* __restrict__ gray,
                                                  const float2* __restrict__ hp,
                                                  const unsigned* __restrict__ cells,
                                                  float* __restrict__ out) {
    __shared__ double sr[2];
    const int t = threadIdx.x;
    if (t < 64) {
        unsigned mn = cells[t];
        unsigned mx = cells[NCELL + t];
        for (int off = 32; off; off >>= 1) {
            unsigned a = __shfl_down(mn, off);
            unsigned b = __shfl_down(mx, off);
            mn = (a < mn) ? a : mn;
            mx = (b > mx) ? b : mx;
        }
        if (t == 0) {
            sr[0] = (double)__uint_as_float(mn);
            sr[1] = (double)__uint_as_float(mx);
        }
    }
    __syncthreads();
    const double r  = 0.5 * (sr[1] - sr[0]);
    const double r2 = r * r;

    const int id   = blockIdx.x;          // 1024 blocks
    const int b    = id & 7;              // batch -> XCD
    const int rest = id >> 3;
    const int ys   = rest & 31;           // y-strip (consecutive on same XCD)
    const int xc   = rest >> 5;           // x quarter (0..3)
    const int x  = xc * 256 + t;          // 1 column per thread
    const int y0 = ys * STRIP;
    const long long ib = (long long)b * IMH * IMW;

    double vx = 0.0, vy = 0.0;            // {h1,h2} running vertical sums (f64 accum)
    #pragma unroll 8
    for (int j = -HALF; j <= HALF; j++) {
        int ry = refl(y0 + j, IMH);
        float2 h = hp[ib + (long long)ry * IMW + x];
        vx += (double)h.x; vy += (double)h.y;
    }

    #pragma unroll 8
    for (int y = y0; y < y0 + STRIP; y++) {
        long long pix = ib + (long long)y * IMW + x;
        double g = (double)gray[pix];

        double m  = vx * INV_AREA;
        double va = fmax(vy * INV_AREA - m * m, 0.0);
        double A  = g - 0.8 * m;
        int o = (A > 0.0) && (A * A * r2 > 0.04 * m * m * va);
        out[pix] = o ? 1.0f : 0.0f;

        int ra = refl(y + HALF + 1, IMH);
        int rs = refl(y - HALF, IMH);
        float2 ha = hp[ib + (long long)ra * IMW + x];
        float2 hs = hp[ib + (long long)rs * IMW + x];
        vx += (double)ha.x - (double)hs.x;
        vy += (double)ha.y - (double)hs.y;
    }
}

extern "C" void kernel_launch(void* const* d_in, const int* in_sizes, int n_in,
                              void* d_out, int out_size, void* d_ws, size_t ws_size,
                              hipStream_t stream) {
    const float* in = (const float*)d_in[0];
    float* out = (float*)d_out;

    unsigned* cells = (unsigned*)d_ws;                          // 2*64 u32
    float2* hp = (float2*)((char*)d_ws + 4096);                 // 67 MB interleaved {h1,h2}
    float* gray = (float*)((char*)d_ws + 4096
                           + (size_t)NB * IMH * IMW * sizeof(float2)); // 33.5 MB staged gray

    hipLaunchKernelGGL(k0_init, dim3(1), dim3(2 * NCELL), 0, stream, cells);
    hipLaunchKernelGGL(k1_rowpass, dim3(NB * IMH / RPB), dim3(256), 0, stream,
                       in, hp, gray, cells);
    hipLaunchKernelGGL(k2_colpass, dim3((IMW / 256) * (IMH / STRIP) * NB), dim3(256), 0, stream,
                       gray, hp, cells, out);
}